// Round 3
// baseline (441.497 us; speedup 1.0000x reference)
//
#include <hip/hip_runtime.h>
#include <cstdint>
#include <cstddef>

#define N_ 32
#define C_ 256
#define H_ 56
#define W_ 56
#define PWORDS 4   // 256 channels / 64 bits

typedef unsigned long long u64;

// workspace layout (bytes)
static constexpr size_t PX_ELEMS = (size_t)N_ * PWORDS * H_ * W_;     // 401408 u64
static constexpr size_t PX_BYTES = PX_ELEMS * 8;                      // 3,211,264
static constexpr size_t PWB_OFF  = PX_BYTES;
static constexpr size_t PW_ELEMS = (size_t)C_ * 9 * PWORDS;           // 9216 u64
static constexpr size_t T_OFF    = PWB_OFF + PW_ELEMS * 8;
static constexpr size_t S_OFF    = T_OFF + (size_t)C_ * 9 * 4;

// ---------------- kernel 1: pack sign bits of x (ballot transpose) ----------
// px layout: [n][word][h][w]. One wave per (n,word,h) row: lane = channel bit.
__global__ __launch_bounds__(256) void pack_x_kernel(const float* __restrict__ x,
                                                     u64* __restrict__ px) {
    int wid  = blockIdx.x * 4 + (threadIdx.x >> 6);   // 0..7167
    int lane = threadIdx.x & 63;
    int h = wid % H_;
    int t = wid / H_;
    int word = t & 3;
    int n    = t >> 2;
    const float* xp = x + ((size_t)(n * C_ + word * 64 + lane)) * (H_ * W_) + h * W_;
    u64 mine = 0;
#pragma unroll 8
    for (int w = 0; w < W_; ++w) {
        u64 bal = __ballot(xp[w] > 0.0f);
        if (lane == w) mine = bal;
    }
    if (lane < W_)
        px[(((size_t)n * PWORDS + word) * H_ + h) * W_ + lane] = mine;
}

// ---------------- kernel 2: binarize weights ----------------
// pw layout: [o][tap][word], tap = kh*3+kw; Tg[o][tap] = 256 - 2*popc256(bits)
__global__ __launch_bounds__(256) void pack_w_kernel(const float* __restrict__ wt,
                                                     u64* __restrict__ pw,
                                                     int* __restrict__ Tg,
                                                     float* __restrict__ scaleg) {
    __shared__ double red[256];
    __shared__ u64 wb[36];
    int o = blockIdx.x, tid = threadIdx.x;
    const float* wo = wt + (size_t)o * 2304;

    double s = 0;
    for (int j = tid; j < 2304; j += 256) s += (double)wo[j];
    red[tid] = s;
    __syncthreads();
    for (int k = 128; k > 0; k >>= 1) {
        if (tid < k) red[tid] += red[tid + k];
        __syncthreads();
    }
    double mean = red[0] / 2304.0;
    __syncthreads();

    double s2 = 0;
    for (int j = tid; j < 2304; j += 256) s2 += fabs((double)wo[j] - mean);
    red[tid] = s2;
    __syncthreads();
    for (int k = 128; k > 0; k >>= 1) {
        if (tid < k) red[tid] += red[tid + k];
        __syncthreads();
    }
    float scale = (float)(red[0] / 2304.0);

    if (tid < 36) {
        int tap = tid >> 2, word = tid & 3;
        u64 bits = 0;
        for (int b = 0; b < 64; ++b) {
            int i = word * 64 + b;
            double v = (double)wo[(size_t)i * 9 + tap];
            bits |= (u64)(v > mean ? 1 : 0) << b;
        }
        wb[tid] = bits;
        pw[(size_t)o * 36 + tid] = bits;
    }
    __syncthreads();
    if (tid < 9) {
        int pc = __popcll(wb[tid * 4]) + __popcll(wb[tid * 4 + 1]) +
                 __popcll(wb[tid * 4 + 2]) + __popcll(wb[tid * 4 + 3]);
        Tg[o * 9 + tid] = 256 - 2 * pc;
    }
    if (tid == 0) scaleg[o] = scale;
}

// ---------------- kernel 3: popcount conv ----------------
// block = 128 threads: hl = tid>>3 (16 rows), wtl = tid&7 (7 w-tiles of 8 used)
// per thread: OT=8 output channels x 8 w outputs. Weights read via wave-uniform
// global loads (scalarized to s_load; xor uses the SGPR operand slot).
#define HT 16
#define OT 8
#define WT 8
#define ROWS 18      // HT + 2 halo
#define COLSP 58     // W_ + 2 halo; [word][row][col] planes, b128-aligned

__global__ __launch_bounds__(128, 2) void conv_kernel(const u64* __restrict__ px,
                                                      const u64* __restrict__ pw,
                                                      const int* __restrict__ Tg,
                                                      const float* __restrict__ scaleg,
                                                      float* __restrict__ out) {
    __shared__ u64 xt[PWORDS * ROWS * COLSP];  // 33408 B

    int tid = threadIdx.x;
    int h0 = blockIdx.x * HT;
    int og = blockIdx.y;
    int n  = blockIdx.z;

    // stage packed x planes (zero-padded halo); contiguous c => coalesced
    for (int i = tid; i < PWORDS * ROWS * COLSP; i += 128) {
        int word = i / (ROWS * COLSP);
        int rem  = i - word * (ROWS * COLSP);
        int r = rem / COLSP;
        int c = rem - r * COLSP;
        int gh = h0 + r - 1, gw = c - 1;
        u64 v = 0;
        if ((unsigned)gh < H_ && (unsigned)gw < W_)
            v = px[(((size_t)n * PWORDS + word) * H_ + gh) * W_ + gw];
        xt[i] = v;
    }
    __syncthreads();

    int hl  = tid >> 3;                 // 0..15
    int wtl = tid & 7;                  // 0..7; only 0..6 store
    int w0  = (wtl < 7 ? wtl : 6) * WT; // even -> b128-aligned LDS reads
    int h   = h0 + hl;

    int acc[OT][WT];
#pragma unroll
    for (int o = 0; o < OT; ++o)
#pragma unroll
        for (int wi = 0; wi < WT; ++wi) acc[o][wi] = 0;

    for (int kh = 0; kh < 3; ++kh) {
        int r = hl + kh;
        for (int word = 0; word < PWORDS; ++word) {
            const u64* row = &xt[(word * ROWS + r) * COLSP + w0];
            u64 xv[WT + 2];
#pragma unroll
            for (int j = 0; j < (WT + 2) / 2; ++j) {
                ulonglong2 p = *(const ulonglong2*)(row + 2 * j);
                xv[2 * j]     = p.x;
                xv[2 * j + 1] = p.y;
            }
            // wave-uniform weight pointer for this (kh, word)
            const u64* wbase = pw + (size_t)(og * OT) * 36 + kh * 12 + word;
#pragma unroll
            for (int o = 0; o < OT; ++o) {
                u64 wv0 = wbase[o * 36];       // kw=0
                u64 wv1 = wbase[o * 36 + 4];   // kw=1
                u64 wv2 = wbase[o * 36 + 8];   // kw=2
#pragma unroll
                for (int wi = 0; wi < WT; ++wi) {
                    acc[o][wi] += __popcll(xv[wi] ^ wv0);
                    acc[o][wi] += __popcll(xv[wi + 1] ^ wv1);
                    acc[o][wi] += __popcll(xv[wi + 2] ^ wv2);
                }
            }
        }
    }

    if (wtl >= 7 || h >= H_) return;

    // border correction: 9-bit invalid-tap masks per output column
    int inv[WT];
#pragma unroll
    for (int wi = 0; wi < WT; ++wi) inv[wi] = 0;
    bool border = (h == 0) | (h == H_ - 1) | (wtl == 0) | (wtl == 6);
    if (border) {
        for (int kh = 0; kh < 3; ++kh) {
            int ih = h + kh - 1;
            bool rI = (unsigned)ih >= H_;
            for (int kw = 0; kw < 3; ++kw) {
                int bit = 1 << (kh * 3 + kw);
                for (int wi = 0; wi < WT; ++wi) {
                    int iw = w0 + wi + kw - 1;
                    if (rI | ((unsigned)iw >= W_)) inv[wi] |= bit;
                }
            }
        }
    }

    size_t obase = ((size_t)(n * C_ + og * OT) * H_ + h) * W_ + w0;
#pragma unroll
    for (int o = 0; o < OT; ++o) {
        float s = scaleg[og * OT + o];
        int corr[WT];
#pragma unroll
        for (int wi = 0; wi < WT; ++wi) corr[wi] = 0;
        if (border) {
            for (int t = 0; t < 9; ++t) {
                int tv = Tg[(og * OT + o) * 9 + t];
                for (int wi = 0; wi < WT; ++wi)
                    if ((inv[wi] >> t) & 1) corr[wi] += tv;
            }
        }
        float4 v0, v1;
        v0.x = s * (float)(2304 - 2 * acc[o][0] - corr[0]);
        v0.y = s * (float)(2304 - 2 * acc[o][1] - corr[1]);
        v0.z = s * (float)(2304 - 2 * acc[o][2] - corr[2]);
        v0.w = s * (float)(2304 - 2 * acc[o][3] - corr[3]);
        v1.x = s * (float)(2304 - 2 * acc[o][4] - corr[4]);
        v1.y = s * (float)(2304 - 2 * acc[o][5] - corr[5]);
        v1.z = s * (float)(2304 - 2 * acc[o][6] - corr[6]);
        v1.w = s * (float)(2304 - 2 * acc[o][7] - corr[7]);
        *(float4*)(out + obase + (size_t)o * (H_ * W_))     = v0;
        *(float4*)(out + obase + (size_t)o * (H_ * W_) + 4) = v1;
    }
}

extern "C" void kernel_launch(void* const* d_in, const int* in_sizes, int n_in,
                              void* d_out, int out_size, void* d_ws, size_t ws_size,
                              hipStream_t stream) {
    const float* x   = (const float*)d_in[0];
    const float* wgt = (const float*)d_in[1];
    float* out = (float*)d_out;
    char* ws = (char*)d_ws;

    u64*   px = (u64*)ws;
    u64*   pw = (u64*)(ws + PWB_OFF);
    int*   Tg = (int*)(ws + T_OFF);
    float* sg = (float*)(ws + S_OFF);

    // 32*4*56 = 7168 waves / 4 per block = 1792 blocks
    pack_x_kernel<<<dim3(1792), dim3(256), 0, stream>>>(x, px);
    pack_w_kernel<<<dim3(256), dim3(256), 0, stream>>>(wgt, pw, Tg, sg);
    conv_kernel<<<dim3(4, C_ / OT, N_), dim3(128), 0, stream>>>(px, pw, Tg, sg, out);
}